// Round 11
// baseline (105.084 us; speedup 1.0000x reference)
//
#include <hip/hip_runtime.h>

#define NPTS 65536
#define WW 1024
#define HWCELLS 65536
#define EPSF 1e-5f
#define QPTS 16

typedef __attribute__((ext_vector_type(8))) short short8;
typedef __attribute__((ext_vector_type(4))) float f32x4;

// tanh-form gelu via exp2+rcp: max |err| vs exact erf-gelu ~3e-4 (below bf16 rounding of g)
__device__ __forceinline__ float gelu_f(float x) {
    float x2 = x * x;
    float q  = fmaf(x2, -0.1029432f, -2.3022160f);   // -(2*0.7978845*[1, 0.044715])*log2(e)
    float e  = __builtin_amdgcn_exp2f(x * q);
    float r  = __builtin_amdgcn_rcpf(1.0f + e);
    return x * r;
}
__device__ __forceinline__ unsigned f2bf_rne(float x) {
    unsigned u = __float_as_uint(x);
    return (u + 0x7fffu + ((u >> 16) & 1u)) >> 16;
}
// HW packed f32x2 -> bf16x2 (RNE on gfx950)
__device__ __forceinline__ unsigned cvtpk(float lo, float hi) {
    unsigned r;
    asm("v_cvt_pk_bf16_f32 %0, %1, %2" : "=v"(r) : "v"(lo), "v"(hi));
    return r;
}

// repack pc -> xn4/xn1 + winner atomicMax (winner pre-memset to -1)
__global__ void prep_k(const float* __restrict__ pc, const int* __restrict__ px,
                       const int* __restrict__ py,
                       float4* __restrict__ xn4, float* __restrict__ xn1,
                       int* __restrict__ winner) {
    int i = blockIdx.x * 256 + threadIdx.x;
    const float* p = &pc[(size_t)i * 5];
    xn4[i] = make_float4(p[0], p[1], p[2], p[3]);
    xn1[i] = p[4];
    int cell = py[i] * WW + px[i];
    atomicMax(&winner[cell], i);
}

// blocks 0..255: inline count(rescan winner) + scan + cell-ordered compaction.
// block 256: weight folding (independent of winner).
__global__ void fillscan2_k(const int* __restrict__ winner,
                            int* __restrict__ ids, int* __restrict__ cells,
                            int* __restrict__ count,
                            const float* __restrict__ ng, const float* __restrict__ nbta,
                            const float* __restrict__ nm, const float* __restrict__ nv,
                            const float* __restrict__ w2a,
                            const float* __restrict__ g2a, const float* __restrict__ b2a,
                            const float* __restrict__ m2a, const float* __restrict__ v2a,
                            const float* __restrict__ g2b, const float* __restrict__ b2b,
                            const float* __restrict__ m2b, const float* __restrict__ v2b,
                            const float* __restrict__ w2b,
                            const float* __restrict__ c1w, const float* __restrict__ c1b,
                            const float* __restrict__ fw, const float* __restrict__ fbias,
                            unsigned short* __restrict__ w2aB8,
                            unsigned short* __restrict__ w2bB,
                            unsigned short* __restrict__ fwallB) {
    const int t = threadIdx.x;

    if (blockIdx.x == 256) {
        // ---- fold block ----
        __shared__ float c1wS[640];
        __shared__ float c1adjS[128];
        const int d = t;
        float s_n[5], t_n[5];
#pragma unroll
        for (int c = 0; c < 5; ++c) {
            s_n[c] = ng[c] * rsqrtf(nv[c] + EPSF);
            t_n[c] = nbta[c] - nm[c] * s_n[c];
        }
        for (int j = t; j < 640; j += 256) c1wS[j] = c1w[j];
        __syncthreads();
        if (t < 128) {
            float a = c1b[d];
#pragma unroll
            for (int c = 0; c < 5; ++c) a += c1wS[d * 5 + c] * t_n[c];
            c1adjS[d] = a;
        }
        __syncthreads();
        if (t >= 128) return;

        float s2b = g2b[d] * rsqrtf(v2b[d] + EPSF);
        float t2b = b2b[d] - m2b[d] * s2b;
        float acc = 0.f;
#pragma unroll
        for (int c = 0; c < 5; ++c) {
            float s2a = g2a[c] * rsqrtf(v2a[c] + EPSF);
            float t2a = b2a[c] - m2a[c] * s2a;
            float wv = w2a[d * 5 + c];
            w2aB8[d * 8 + c] = (unsigned short)f2bf_rne(s2b * wv * s2a * s_n[c]);
            acc += s2b * wv * t2a;
        }
        w2aB8[d * 8 + 5] = (unsigned short)f2bf_rne(acc + t2b);  // bias via dx[5]=1
        w2aB8[d * 8 + 6] = 0; w2aB8[d * 8 + 7] = 0;

#pragma unroll 8
        for (int i4 = 0; i4 < 32; ++i4) {
            float4 v = *(const float4*)&w2b[d * 128 + i4 * 4];
            unsigned short* dst = &w2bB[d * 128 + i4 * 4];
            dst[0] = (unsigned short)f2bf_rne(v.x);
            dst[1] = (unsigned short)f2bf_rne(v.y);
            dst[2] = (unsigned short)f2bf_rne(v.z);
            dst[3] = (unsigned short)f2bf_rne(v.w);
        }

        float f1[5] = {0.f, 0.f, 0.f, 0.f, 0.f};
        float fbv = fbias[d];
#pragma unroll 8
        for (int d4 = 0; d4 < 32; ++d4) {
            float4 fv = *(const float4*)&fw[d * 256 + d4 * 4];
            float4 fn = *(const float4*)&fw[d * 256 + 128 + d4 * 4];
            unsigned short* dst = &fwallB[d * 160 + d4 * 4];
            dst[0] = (unsigned short)f2bf_rne(fn.x);
            dst[1] = (unsigned short)f2bf_rne(fn.y);
            dst[2] = (unsigned short)f2bf_rne(fn.z);
            dst[3] = (unsigned short)f2bf_rne(fn.w);
            int dd = d4 * 4;
            fbv += fv.x * c1adjS[dd] + fv.y * c1adjS[dd+1] + fv.z * c1adjS[dd+2] + fv.w * c1adjS[dd+3];
#pragma unroll
            for (int c = 0; c < 5; ++c)
                f1[c] += fv.x * c1wS[dd*5 + c] + fv.y * c1wS[(dd+1)*5 + c]
                       + fv.z * c1wS[(dd+2)*5 + c] + fv.w * c1wS[(dd+3)*5 + c];
        }
#pragma unroll
        for (int c = 0; c < 5; ++c)
            fwallB[d * 160 + 128 + c] = (unsigned short)f2bf_rne(f1[c] * s_n[c]);
        fwallB[d * 160 + 133] = (unsigned short)f2bf_rne(fbv);
        for (int j = 134; j < 160; ++j) fwallB[d * 160 + j] = 0;
        return;
    }

    // ---- scan+fill blocks ----
    __shared__ int gcnt[256];
    __shared__ int sarr[256];
    __shared__ int wcnt[4];
    const int lane = t & 63, wv = t >> 6;

    // count phase: all 256 group counts from winner (L2-resident, uint4 loads)
    const uint4* w4 = (const uint4*)winner;   // 16384 entries
#pragma unroll 4
    for (int j = 0; j < 64; ++j) {
        uint4 v = w4[j * 256 + t];            // cells j*1024 + t*4 .. +3 (group j*4+wv)
        int c = ((int)v.x >= 0) + ((int)v.y >= 0) + ((int)v.z >= 0) + ((int)v.w >= 0);
#pragma unroll
        for (int off = 32; off; off >>= 1) c += __shfl_down(c, off);
        if (lane == 0) gcnt[j * 4 + wv] = c;
    }
    __syncthreads();

    int orig = gcnt[t];
    sarr[t] = orig;
    __syncthreads();
    for (int off = 1; off < 256; off <<= 1) {
        int v = (t >= off) ? sarr[t - off] : 0;
        __syncthreads();
        sarr[t] += v;
        __syncthreads();
    }
    if (blockIdx.x == 0 && t == 255) *count = sarr[255];
    int excl = sarr[blockIdx.x] - gcnt[blockIdx.x];

    int cell = blockIdx.x * 256 + t;
    int win = winner[cell];
    bool occ = win >= 0;
    unsigned long long m = __ballot(occ);
    if (lane == 0) wcnt[wv] = __popcll(m);
    __syncthreads();
    int woff = excl;
    for (int i = 0; i < wv; ++i) woff += wcnt[i];
    if (occ) {
        int lrank = __popcll(m & ((1ull << lane) - 1));
        ids[woff + lrank] = win;
        cells[woff + lrank] = cell;
    }
}

// fused MFMA main: 16 pts/block, 256 thr (4 waves); no global traffic in k-loop.
// Epilogue: each block writes its FULL cell span [cells[n0], cells[n0+16]) for
// all 128 e — winner columns from LDS feats, gaps = -1 — fully coalesced, and
// covers `out` exactly once (no pre-fill kernel needed).
__launch_bounds__(256, 6)
__global__ void main_k(const int* __restrict__ ids, const int* __restrict__ cells,
                       const int* __restrict__ countp,
                       const int* __restrict__ nbrs,
                       const float4* __restrict__ xn4, const float* __restrict__ xn1,
                       const unsigned short* __restrict__ w2aB8,
                       const unsigned short* __restrict__ w2bB,
                       const unsigned short* __restrict__ fwallB,
                       float* __restrict__ outp) {
    const int cnt = *countp;
    const int n0 = blockIdx.x * QPTS;
    if (n0 >= cnt) return;

    __shared__ char           lds[8448];          // G dbuf (2x4096); M (5120); feats (8448)
    __shared__ unsigned short dxS[15 * 16 * 8];   // bf16 [kk][pt][8]; reused as slotmap
    __shared__ int   idS[QPTS];
    __shared__ int   nbS[QPTS * 16];
    __shared__ float xnS[QPTS][5];
    __shared__ int   cellS[QPTS];

    const int t = threadIdx.x;
    const int w = t >> 6;
    const int l = t & 63;
    const int l15 = l & 15;
    const int lg  = l >> 4;

    if (t < QPTS) {
        int slot = n0 + t;
        slot = slot < cnt ? slot : cnt - 1;
        idS[t] = ids[slot];
        cellS[t] = cells[slot];
    }
    __syncthreads();

    nbS[t] = nbrs[idS[t >> 4] * 16 + (t & 15)];
    if (t < QPTS) {
        int id = idS[t];
        float4 a = xn4[id];
        xnS[t][0] = a.x; xnS[t][1] = a.y; xnS[t][2] = a.z; xnS[t][3] = a.w;
        xnS[t][4] = xn1[id];
    }

    // A1: folded W2A'|bias rows (only lg==0 lanes carry k=0..7; rest zero)
    short8 a1[2] = { {0,0,0,0,0,0,0,0}, {0,0,0,0,0,0,0,0} };
    if (lg == 0) {
        a1[0] = *(const short8*)(w2aB8 + (w * 32 + l15) * 8);
        a1[1] = *(const short8*)(w2aB8 + (w * 32 + 16 + l15) * 8);
    }
    // A2: w2b rows [w*32, w*32+32), K=128
    short8 a2[2][4];
#pragma unroll
    for (int rt = 0; rt < 2; ++rt)
#pragma unroll
        for (int ks = 0; ks < 4; ++ks)
            a2[rt][ks] = *(const short8*)(w2bB + (w * 32 + rt * 16 + l15) * 128 + ks * 32 + lg * 8);

    __syncthreads();  // nbS + xnS ready

    // build dx tile: one gather per (pt,kk)
    if (t < 240) {
        int pt = t & 15, kk = t >> 4;
        int nb = nbS[pt * 16 + kk + 1];
        float4 a = xn4[nb];
        float  e = xn1[nb];
        float d0 = a.x - xnS[pt][0];
        float d1 = a.y - xnS[pt][1];
        float d2 = a.z - xnS[pt][2];
        float d3 = a.w - xnS[pt][3];
        float d4 = e   - xnS[pt][4];
        uint4 v;
        v.x = cvtpk(d0, d1);
        v.y = cvtpk(d2, d3);
        v.z = cvtpk(d4, 1.0f);
        v.w = 0u;
        *(uint4*)&dxS[(kk * 16 + pt) * 8] = v;
    }
    __syncthreads();  // dxS ready

    const f32x4 zero4 = {0.f, 0.f, 0.f, 0.f};
    f32x4 mmax[2];
#pragma unroll
    for (int rt = 0; rt < 2; ++rt)
#pragma unroll
        for (int j = 0; j < 4; ++j) mmax[rt][j] = -1e30f;

    for (int kk = 0; kk < 15; ++kk) {
        // MFMA1: s[din][pt] = W2A'|b2 @ [dx;1]  (broadcast LDS read; lg!=0 rows of A are 0)
        short8 dxf = *(const short8*)&dxS[(kk * 16 + l15) * 8];
        char* Gb = lds + (kk & 1) * 4096;
#pragma unroll
        for (int rt = 0; rt < 2; ++rt) {
            f32x4 s = __builtin_amdgcn_mfma_f32_16x16x32_bf16(a1[rt], dxf, zero4, 0, 0, 0);
            uint2 pr;
            pr.x = cvtpk(gelu_f(s[0]), gelu_f(s[1]));
            pr.y = cvtpk(gelu_f(s[2]), gelu_f(s[3]));
            int din0 = w * 32 + rt * 16 + lg * 4;
            *(uint2*)(Gb + l15 * 256 + ((din0 * 2) ^ (l15 << 4))) = pr;
        }
        __syncthreads();
        // MFMA2: u = w2b @ G; running max
        f32x4 acc[2];
        __builtin_amdgcn_s_setprio(1);
#pragma unroll
        for (int ks = 0; ks < 4; ++ks) {
            int kb = (ks * 32 + lg * 8) * 2;
            short8 bfrag = *(const short8*)(Gb + l15 * 256 + (kb ^ (l15 << 4)));
#pragma unroll
            for (int rt = 0; rt < 2; ++rt)
                acc[rt] = __builtin_amdgcn_mfma_f32_16x16x32_bf16(
                    a2[rt][ks], bfrag, ks == 0 ? zero4 : acc[rt], 0, 0, 0);
        }
        __builtin_amdgcn_s_setprio(0);
#pragma unroll
        for (int rt = 0; rt < 2; ++rt)
#pragma unroll
            for (int j = 0; j < 4; ++j)
                mmax[rt][j] = fmaxf(mmax[rt][j], acc[rt][j]);
    }

    __syncthreads();  // all MFMA2 reads done before M overlay

    // running max -> M [pt][k] bf16 (k<128 swizzled) + xn|1 tail (k=128..)
    {
        char* Mb = lds;
        int sw = l15 << 4;
#pragma unroll
        for (int rt = 0; rt < 2; ++rt) {
            int dout = w * 32 + rt * 16 + lg * 4;
            unsigned lo = cvtpk(mmax[rt][0], mmax[rt][1]);
            unsigned hi = cvtpk(mmax[rt][2], mmax[rt][3]);
            *(unsigned*)(Mb + l15 * 320 + ((dout * 2) ^ sw)) = lo;
            *(unsigned*)(Mb + l15 * 320 + (((dout + 2) * 2) ^ sw)) = hi;
        }
        if (t < QPTS) {
            uint4 a;
            a.x = cvtpk(xnS[t][0], xnS[t][1]);
            a.y = cvtpk(xnS[t][2], xnS[t][3]);
            a.z = cvtpk(xnS[t][4], 1.0f);
            a.w = 0u;
            uint4 z; z.x = 0u; z.y = 0u; z.z = 0u; z.w = 0u;
            *(uint4*)(Mb + t * 320 + 256) = a;
            *(uint4*)(Mb + t * 320 + 272) = z;
            *(uint4*)(Mb + t * 320 + 288) = z;
            *(uint4*)(Mb + t * 320 + 304) = z;
        }
    }
    __syncthreads();

    // final GEMM: feats[e][pt] = fwallB(128x160) @ M(160xQPTS)
    f32x4 facc[2];
    const char* Mr = lds;
#pragma unroll
    for (int ks = 0; ks < 5; ++ks) {
        short8 af[2];
#pragma unroll
        for (int rt = 0; rt < 2; ++rt)
            af[rt] = *(const short8*)(fwallB + (w * 32 + rt * 16 + l15) * 160 + ks * 32 + lg * 8);
        int kb = (ks * 32 + lg * 8) * 2;
        int kbs = (kb < 256) ? (kb ^ (l15 << 4)) : kb;
        short8 bfr = *(const short8*)(Mr + l15 * 320 + kbs);
#pragma unroll
        for (int rt = 0; rt < 2; ++rt)
            facc[rt] = __builtin_amdgcn_mfma_f32_16x16x32_bf16(
                af[rt], bfr, ks == 0 ? zero4 : facc[rt], 0, 0, 0);
    }

    __syncthreads();  // all waves done reading M before feats overlay

    // feats -> LDS [pt][132] f32 (pad 132: slot*132 words mod 32 varies -> <=2-way)
    float* featsF = (float*)lds;
#pragma unroll
    for (int rt = 0; rt < 2; ++rt) {
        int e0 = w * 32 + rt * 16 + lg * 4;
#pragma unroll
        for (int j = 0; j < 4; ++j)
            featsF[l15 * 132 + e0 + j] = facc[rt][j];
    }

    // span write: cells [c0, cend) for all 128 e; winner cols from feats, gaps -1
    int* slotmap = (int*)dxS;   // 960 ints
    const int cend = (n0 + QPTS >= cnt) ? HWCELLS : cells[n0 + QPTS];
    const int c0 = (blockIdx.x == 0) ? 0 : cellS[0];
    __syncthreads();  // featsF complete

    for (int chunk0 = c0; chunk0 < cend; chunk0 += 960) {
        int L = cend - chunk0; L = L < 960 ? L : 960;
        for (int i = t; i < L; i += 256) slotmap[i] = -1;
        __syncthreads();
        if (t < QPTS) {
            int cc = cellS[t];
            if (cc >= chunk0 && cc < chunk0 + L) slotmap[cc - chunk0] = t;
        }
        __syncthreads();
        int ci0 = t & 31, eq = t >> 5;   // 8 e-rows x 32 cells per pass
#pragma unroll 4
        for (int ep = 0; ep < 16; ++ep) {
            int e = ep * 8 + eq;
            float* orow = outp + (size_t)e * HWCELLS + chunk0;
            for (int cb = ci0; cb < L; cb += 32) {
                int slot = slotmap[cb];
                float v = (slot >= 0) ? featsF[slot * 132 + e] : -1.0f;
                orow[cb] = v;
            }
        }
        __syncthreads();
    }
}

extern "C" void kernel_launch(void* const* d_in, const int* in_sizes, int n_in,
                              void* d_out, int out_size, void* d_ws, size_t ws_size,
                              hipStream_t stream) {
    const float* pc        = (const float*)d_in[0];
    const int*   neighbors = (const int*)d_in[1];
    const int*   px        = (const int*)d_in[2];
    const int*   py        = (const int*)d_in[3];
    const float* norm_g    = (const float*)d_in[4];
    const float* norm_b    = (const float*)d_in[5];
    const float* norm_m    = (const float*)d_in[6];
    const float* norm_v    = (const float*)d_in[7];
    const float* conv1_w   = (const float*)d_in[8];
    const float* conv1_b   = (const float*)d_in[9];
    const float* bn2a_g    = (const float*)d_in[10];
    const float* bn2a_b    = (const float*)d_in[11];
    const float* bn2a_m    = (const float*)d_in[12];
    const float* bn2a_v    = (const float*)d_in[13];
    const float* w2a       = (const float*)d_in[14];
    const float* bn2b_g    = (const float*)d_in[15];
    const float* bn2b_b    = (const float*)d_in[16];
    const float* bn2b_m    = (const float*)d_in[17];
    const float* bn2b_v    = (const float*)d_in[18];
    const float* w2b       = (const float*)d_in[19];
    const float* final_w   = (const float*)d_in[20];
    const float* final_b   = (const float*)d_in[21];
    float* out = (float*)d_out;

    char* ws = (char*)d_ws;
    float4*         xn4      = (float4*)(ws);                     // 1,048,576 B
    float*          xn1      = (float*)(ws + 1048576);            //   262,144 B
    int*            winner   = (int*)(ws + 1310720);              //   262,144 B
    int*            ids      = (int*)(ws + 1572864);              //   262,144 B
    int*            cells    = (int*)(ws + 1835008);              //   262,144 B
    int*            count    = (int*)(ws + 2097152);              //       256 B
    unsigned short* w2aB8    = (unsigned short*)(ws + 2097408);   //     2,048 B
    unsigned short* w2bB     = (unsigned short*)(ws + 2099456);   //    32,768 B
    unsigned short* fwallB   = (unsigned short*)(ws + 2132224);   //    40,960 B

    // winner = -1 via byte-fill (graph-capture-safe async memset)
    hipMemsetAsync(winner, 0xFF, 262144, stream);
    prep_k<<<256, 256, 0, stream>>>(pc, px, py, xn4, xn1, winner);
    fillscan2_k<<<257, 256, 0, stream>>>(winner, ids, cells, count,
                                         norm_g, norm_b, norm_m, norm_v,
                                         w2a, bn2a_g, bn2a_b, bn2a_m, bn2a_v,
                                         bn2b_g, bn2b_b, bn2b_m, bn2b_v, w2b,
                                         conv1_w, conv1_b, final_w, final_b,
                                         w2aB8, w2bB, fwallB);
    main_k<<<4096, 256, 0, stream>>>(ids, cells, count, neighbors, xn4, xn1,
                                     w2aB8, w2bB, fwallB, out);
}

// Round 14
// 97.320 us; speedup vs baseline: 1.0798x; 1.0798x over previous
//
#include <hip/hip_runtime.h>

#define NPTS 65536
#define WW 1024
#define HWCELLS 65536
#define EPSF 1e-5f
#define QPTS 16

typedef __attribute__((ext_vector_type(8))) short short8;
typedef __attribute__((ext_vector_type(4))) float f32x4;

// tanh-form gelu via exp2+rcp: max |err| vs exact erf-gelu ~3e-4 (below bf16 rounding of g)
__device__ __forceinline__ float gelu_f(float x) {
    float x2 = x * x;
    float q  = fmaf(x2, -0.1029432f, -2.3022160f);   // -(2*0.7978845*[1, 0.044715])*log2(e)
    float e  = __builtin_amdgcn_exp2f(x * q);
    float r  = __builtin_amdgcn_rcpf(1.0f + e);
    return x * r;
}
__device__ __forceinline__ unsigned f2bf_rne(float x) {
    unsigned u = __float_as_uint(x);
    return (u + 0x7fffu + ((u >> 16) & 1u)) >> 16;
}
// HW packed f32x2 -> bf16x2 (RNE on gfx950)
__device__ __forceinline__ unsigned cvtpk(float lo, float hi) {
    unsigned r;
    asm("v_cvt_pk_bf16_f32 %0, %1, %2" : "=v"(r) : "v"(lo), "v"(hi));
    return r;
}

// blocks 0..255: repack pc + winner atomicMax;  block 256: weight folding + count=0
__global__ void prepfold_k(const float* __restrict__ pc, const int* __restrict__ px,
                           const int* __restrict__ py,
                           float4* __restrict__ xn4, float* __restrict__ xn1,
                           int* __restrict__ winner, int* __restrict__ countp,
                           const float* __restrict__ ng, const float* __restrict__ nbta,
                           const float* __restrict__ nm, const float* __restrict__ nv,
                           const float* __restrict__ w2a,
                           const float* __restrict__ g2a, const float* __restrict__ b2a,
                           const float* __restrict__ m2a, const float* __restrict__ v2a,
                           const float* __restrict__ g2b, const float* __restrict__ b2b,
                           const float* __restrict__ m2b, const float* __restrict__ v2b,
                           const float* __restrict__ w2b,
                           const float* __restrict__ c1w, const float* __restrict__ c1b,
                           const float* __restrict__ fw, const float* __restrict__ fbias,
                           unsigned short* __restrict__ w2aB8,
                           unsigned short* __restrict__ w2bB,
                           unsigned short* __restrict__ fwallB) {
    __shared__ float c1wS[640];
    __shared__ float c1adjS[128];
    const int t = threadIdx.x;

    if (blockIdx.x < 256) {
        int i = blockIdx.x * 256 + t;
        const float* p = &pc[(size_t)i * 5];
        xn4[i] = make_float4(p[0], p[1], p[2], p[3]);
        xn1[i] = p[4];
        int cell = py[i] * WW + px[i];
        atomicMax(&winner[cell], i);
        return;
    }

    // ---- fold block (all 256 threads participate in barriers; work on t<128) ----
    const int d = t;  // 0..127 used
    float s_n[5], t_n[5];
#pragma unroll
    for (int c = 0; c < 5; ++c) {
        s_n[c] = ng[c] * rsqrtf(nv[c] + EPSF);
        t_n[c] = nbta[c] - nm[c] * s_n[c];
    }
    for (int j = t; j < 640; j += 256) c1wS[j] = c1w[j];
    __syncthreads();
    if (t < 128) {
        float a = c1b[d];
#pragma unroll
        for (int c = 0; c < 5; ++c) a += c1wS[d * 5 + c] * t_n[c];
        c1adjS[d] = a;
    }
    __syncthreads();
    if (t >= 128) {
        if (t == 128) *countp = 0;   // zero the compaction counter each call
        return;
    }

    float s2b = g2b[d] * rsqrtf(v2b[d] + EPSF);
    float t2b = b2b[d] - m2b[d] * s2b;
    float acc = 0.f;
#pragma unroll
    for (int c = 0; c < 5; ++c) {
        float s2a = g2a[c] * rsqrtf(v2a[c] + EPSF);
        float t2a = b2a[c] - m2a[c] * s2a;
        float wv = w2a[d * 5 + c];
        w2aB8[d * 8 + c] = (unsigned short)f2bf_rne(s2b * wv * s2a * s_n[c]);
        acc += s2b * wv * t2a;
    }
    w2aB8[d * 8 + 5] = (unsigned short)f2bf_rne(acc + t2b);  // bias via dx[5]=1
    w2aB8[d * 8 + 6] = 0; w2aB8[d * 8 + 7] = 0;

#pragma unroll 8
    for (int i4 = 0; i4 < 32; ++i4) {
        float4 v = *(const float4*)&w2b[d * 128 + i4 * 4];
        unsigned short* dst = &w2bB[d * 128 + i4 * 4];
        dst[0] = (unsigned short)f2bf_rne(v.x);
        dst[1] = (unsigned short)f2bf_rne(v.y);
        dst[2] = (unsigned short)f2bf_rne(v.z);
        dst[3] = (unsigned short)f2bf_rne(v.w);
    }

    float f1[5] = {0.f, 0.f, 0.f, 0.f, 0.f};
    float fbv = fbias[d];
#pragma unroll 8
    for (int d4 = 0; d4 < 32; ++d4) {
        float4 fv = *(const float4*)&fw[d * 256 + d4 * 4];
        float4 fn = *(const float4*)&fw[d * 256 + 128 + d4 * 4];
        unsigned short* dst = &fwallB[d * 160 + d4 * 4];
        dst[0] = (unsigned short)f2bf_rne(fn.x);
        dst[1] = (unsigned short)f2bf_rne(fn.y);
        dst[2] = (unsigned short)f2bf_rne(fn.z);
        dst[3] = (unsigned short)f2bf_rne(fn.w);
        int dd = d4 * 4;
        fbv += fv.x * c1adjS[dd] + fv.y * c1adjS[dd+1] + fv.z * c1adjS[dd+2] + fv.w * c1adjS[dd+3];
#pragma unroll
        for (int c = 0; c < 5; ++c)
            f1[c] += fv.x * c1wS[dd*5 + c] + fv.y * c1wS[(dd+1)*5 + c]
                   + fv.z * c1wS[(dd+2)*5 + c] + fv.w * c1wS[(dd+3)*5 + c];
    }
#pragma unroll
    for (int c = 0; c < 5; ++c)
        fwallB[d * 160 + 128 + c] = (unsigned short)f2bf_rne(f1[c] * s_n[c]);
    fwallB[d * 160 + 133] = (unsigned short)f2bf_rne(fbv);
    for (int j = 134; j < 160; ++j) fwallB[d * 160 + j] = 0;
}

// all 1024 blocks: out -1 prefill.  blocks 0..255: count own group's winners,
// atomicAdd for a group base slot, fill ids/cells (cell-ascending WITHIN group).
__global__ void cntfillout_k(float4* __restrict__ out4,
                             const int* __restrict__ winner,
                             int* __restrict__ ids, int* __restrict__ cells,
                             int* __restrict__ countp) {
    int gid = blockIdx.x * 256 + threadIdx.x;
    float4 mone = make_float4(-1.f, -1.f, -1.f, -1.f);
#pragma unroll
    for (int j = 0; j < 8; ++j) out4[gid + j * 262144] = mone;
    if (blockIdx.x >= 256) return;

    __shared__ int wcnt[4];
    __shared__ int gbase;
    int lane = threadIdx.x & 63, wv = threadIdx.x >> 6;
    int cell = gid;
    int win = winner[cell];
    bool occ = win >= 0;
    unsigned long long m = __ballot(occ);
    if (lane == 0) wcnt[wv] = __popcll(m);
    __syncthreads();
    if (threadIdx.x == 0) {
        int c = wcnt[0] + wcnt[1] + wcnt[2] + wcnt[3];
        gbase = atomicAdd(countp, c);
    }
    __syncthreads();
    int woff = gbase;
    for (int i = 0; i < wv; ++i) woff += wcnt[i];
    if (occ) {
        int lrank = __popcll(m & ((1ull << lane) - 1));
        ids[woff + lrank] = win;
        cells[woff + lrank] = cell;
    }
}

// fused MFMA main: 16 pts/block, 256 thr (4 waves); no global traffic in k-loop
// (byte-identical to the round-8 proven body)
__launch_bounds__(256, 6)
__global__ void main_k(const int* __restrict__ ids, const int* __restrict__ cells,
                       const int* __restrict__ countp,
                       const int* __restrict__ nbrs,
                       const float4* __restrict__ xn4, const float* __restrict__ xn1,
                       const unsigned short* __restrict__ w2aB8,
                       const unsigned short* __restrict__ w2bB,
                       const unsigned short* __restrict__ fwallB,
                       float* __restrict__ outp) {
    const int cnt = *countp;
    const int n0 = blockIdx.x * QPTS;
    if (n0 >= cnt) return;

    __shared__ char           lds[8192];          // G dbuf (2x4096); M (5120) overlays
    __shared__ unsigned short dxS[15 * 16 * 8];   // bf16 [kk][pt][8]: dx0..4,1.0,0,0
    __shared__ int   idS[QPTS];
    __shared__ int   nbS[QPTS * 16];
    __shared__ float xnS[QPTS][5];
    __shared__ int   cellS[QPTS];

    const int t = threadIdx.x;
    const int w = t >> 6;
    const int l = t & 63;
    const int l15 = l & 15;
    const int lg  = l >> 4;

    if (t < QPTS) {
        int slot = n0 + t;
        slot = slot < cnt ? slot : cnt - 1;
        idS[t] = ids[slot];
        cellS[t] = cells[slot];
    }
    __syncthreads();

    nbS[t] = nbrs[idS[t >> 4] * 16 + (t & 15)];
    if (t < QPTS) {
        int id = idS[t];
        float4 a = xn4[id];
        xnS[t][0] = a.x; xnS[t][1] = a.y; xnS[t][2] = a.z; xnS[t][3] = a.w;
        xnS[t][4] = xn1[id];
    }

    // A1: folded W2A'|bias rows (only lg==0 lanes carry k=0..7; rest zero)
    short8 a1[2] = { {0,0,0,0,0,0,0,0}, {0,0,0,0,0,0,0,0} };
    if (lg == 0) {
        a1[0] = *(const short8*)(w2aB8 + (w * 32 + l15) * 8);
        a1[1] = *(const short8*)(w2aB8 + (w * 32 + 16 + l15) * 8);
    }
    // A2: w2b rows [w*32, w*32+32), K=128
    short8 a2[2][4];
#pragma unroll
    for (int rt = 0; rt < 2; ++rt)
#pragma unroll
        for (int ks = 0; ks < 4; ++ks)
            a2[rt][ks] = *(const short8*)(w2bB + (w * 32 + rt * 16 + l15) * 128 + ks * 32 + lg * 8);

    __syncthreads();  // nbS + xnS ready

    // build dx tile: one gather per (pt,kk)
    if (t < 240) {
        int pt = t & 15, kk = t >> 4;
        int nb = nbS[pt * 16 + kk + 1];
        float4 a = xn4[nb];
        float  e = xn1[nb];
        float d0 = a.x - xnS[pt][0];
        float d1 = a.y - xnS[pt][1];
        float d2 = a.z - xnS[pt][2];
        float d3 = a.w - xnS[pt][3];
        float d4 = e   - xnS[pt][4];
        uint4 v;
        v.x = cvtpk(d0, d1);
        v.y = cvtpk(d2, d3);
        v.z = cvtpk(d4, 1.0f);
        v.w = 0u;
        *(uint4*)&dxS[(kk * 16 + pt) * 8] = v;
    }
    __syncthreads();  // dxS ready

    const f32x4 zero4 = {0.f, 0.f, 0.f, 0.f};
    f32x4 mmax[2];
#pragma unroll
    for (int rt = 0; rt < 2; ++rt)
#pragma unroll
        for (int j = 0; j < 4; ++j) mmax[rt][j] = -1e30f;

    for (int kk = 0; kk < 15; ++kk) {
        // MFMA1: s[din][pt] = W2A'|b2 @ [dx;1]  (broadcast LDS read; lg!=0 rows of A are 0)
        short8 dxf = *(const short8*)&dxS[(kk * 16 + l15) * 8];
        char* Gb = lds + (kk & 1) * 4096;
#pragma unroll
        for (int rt = 0; rt < 2; ++rt) {
            f32x4 s = __builtin_amdgcn_mfma_f32_16x16x32_bf16(a1[rt], dxf, zero4, 0, 0, 0);
            uint2 pr;
            pr.x = cvtpk(gelu_f(s[0]), gelu_f(s[1]));
            pr.y = cvtpk(gelu_f(s[2]), gelu_f(s[3]));
            int din0 = w * 32 + rt * 16 + lg * 4;
            *(uint2*)(Gb + l15 * 256 + ((din0 * 2) ^ (l15 << 4))) = pr;
        }
        __syncthreads();
        // MFMA2: u = w2b @ G; running max
        f32x4 acc[2];
        __builtin_amdgcn_s_setprio(1);
#pragma unroll
        for (int ks = 0; ks < 4; ++ks) {
            int kb = (ks * 32 + lg * 8) * 2;
            short8 bfrag = *(const short8*)(Gb + l15 * 256 + (kb ^ (l15 << 4)));
#pragma unroll
            for (int rt = 0; rt < 2; ++rt)
                acc[rt] = __builtin_amdgcn_mfma_f32_16x16x32_bf16(
                    a2[rt][ks], bfrag, ks == 0 ? zero4 : acc[rt], 0, 0, 0);
        }
        __builtin_amdgcn_s_setprio(0);
#pragma unroll
        for (int rt = 0; rt < 2; ++rt)
#pragma unroll
            for (int j = 0; j < 4; ++j)
                mmax[rt][j] = fmaxf(mmax[rt][j], acc[rt][j]);
    }

    __syncthreads();  // all MFMA2 reads done before M overlay

    // running max -> M [pt][k] bf16 (k<128 swizzled) + xn|1 tail (k=128..)
    {
        char* Mb = lds;
        int sw = l15 << 4;
#pragma unroll
        for (int rt = 0; rt < 2; ++rt) {
            int dout = w * 32 + rt * 16 + lg * 4;
            unsigned lo = cvtpk(mmax[rt][0], mmax[rt][1]);
            unsigned hi = cvtpk(mmax[rt][2], mmax[rt][3]);
            *(unsigned*)(Mb + l15 * 320 + ((dout * 2) ^ sw)) = lo;
            *(unsigned*)(Mb + l15 * 320 + (((dout + 2) * 2) ^ sw)) = hi;
        }
        if (t < QPTS) {
            uint4 a;
            a.x = cvtpk(xnS[t][0], xnS[t][1]);
            a.y = cvtpk(xnS[t][2], xnS[t][3]);
            a.z = cvtpk(xnS[t][4], 1.0f);
            a.w = 0u;
            uint4 z; z.x = 0u; z.y = 0u; z.z = 0u; z.w = 0u;
            *(uint4*)(Mb + t * 320 + 256) = a;
            *(uint4*)(Mb + t * 320 + 272) = z;
            *(uint4*)(Mb + t * 320 + 288) = z;
            *(uint4*)(Mb + t * 320 + 304) = z;
        }
    }
    __syncthreads();

    // final GEMM: feats[e][pt] = fwallB(128x160) @ M(160xQPTS)
    f32x4 facc[2];
    const char* Mr = lds;
#pragma unroll
    for (int ks = 0; ks < 5; ++ks) {
        short8 af[2];
#pragma unroll
        for (int rt = 0; rt < 2; ++rt)
            af[rt] = *(const short8*)(fwallB + (w * 32 + rt * 16 + l15) * 160 + ks * 32 + lg * 8);
        int kb = (ks * 32 + lg * 8) * 2;
        int kbs = (kb < 256) ? (kb ^ (l15 << 4)) : kb;
        short8 bfr = *(const short8*)(Mr + l15 * 320 + kbs);
#pragma unroll
        for (int rt = 0; rt < 2; ++rt)
            facc[rt] = __builtin_amdgcn_mfma_f32_16x16x32_bf16(
                af[rt], bfr, ks == 0 ? zero4 : facc[rt], 0, 0, 0);
    }

    // direct scatter: cells ascending within group -> near-coalesced lines
    const int cell = cellS[l15];
#pragma unroll
    for (int rt = 0; rt < 2; ++rt) {
        int e0 = w * 32 + rt * 16 + lg * 4;
#pragma unroll
        for (int j = 0; j < 4; ++j)
            outp[(size_t)(e0 + j) * HWCELLS + cell] = facc[rt][j];
    }
}

extern "C" void kernel_launch(void* const* d_in, const int* in_sizes, int n_in,
                              void* d_out, int out_size, void* d_ws, size_t ws_size,
                              hipStream_t stream) {
    const float* pc        = (const float*)d_in[0];
    const int*   neighbors = (const int*)d_in[1];
    const int*   px        = (const int*)d_in[2];
    const int*   py        = (const int*)d_in[3];
    const float* norm_g    = (const float*)d_in[4];
    const float* norm_b    = (const float*)d_in[5];
    const float* norm_m    = (const float*)d_in[6];
    const float* norm_v    = (const float*)d_in[7];
    const float* conv1_w   = (const float*)d_in[8];
    const float* conv1_b   = (const float*)d_in[9];
    const float* bn2a_g    = (const float*)d_in[10];
    const float* bn2a_b    = (const float*)d_in[11];
    const float* bn2a_m    = (const float*)d_in[12];
    const float* bn2a_v    = (const float*)d_in[13];
    const float* w2a       = (const float*)d_in[14];
    const float* bn2b_g    = (const float*)d_in[15];
    const float* bn2b_b    = (const float*)d_in[16];
    const float* bn2b_m    = (const float*)d_in[17];
    const float* bn2b_v    = (const float*)d_in[18];
    const float* w2b       = (const float*)d_in[19];
    const float* final_w   = (const float*)d_in[20];
    const float* final_b   = (const float*)d_in[21];
    float* out = (float*)d_out;

    char* ws = (char*)d_ws;
    float4*         xn4      = (float4*)(ws);                     // 1,048,576 B
    float*          xn1      = (float*)(ws + 1048576);            //   262,144 B
    int*            winner   = (int*)(ws + 1310720);              //   262,144 B
    int*            ids      = (int*)(ws + 1572864);              //   262,144 B
    int*            cells    = (int*)(ws + 1835008);              //   262,144 B
    int*            count    = (int*)(ws + 2097152);              //       256 B
    unsigned short* w2aB8    = (unsigned short*)(ws + 2097408);   //     2,048 B
    unsigned short* w2bB     = (unsigned short*)(ws + 2099456);   //    32,768 B
    unsigned short* fwallB   = (unsigned short*)(ws + 2132224);   //    40,960 B

    // winner = -1 via byte-fill (graph-capture-safe async memset)
    hipMemsetAsync(winner, 0xFF, 262144, stream);
    prepfold_k<<<257, 256, 0, stream>>>(pc, px, py, xn4, xn1, winner, count,
                                        norm_g, norm_b, norm_m, norm_v,
                                        w2a, bn2a_g, bn2a_b, bn2a_m, bn2a_v,
                                        bn2b_g, bn2b_b, bn2b_m, bn2b_v, w2b,
                                        conv1_w, conv1_b, final_w, final_b,
                                        w2aB8, w2bB, fwallB);
    cntfillout_k<<<1024, 256, 0, stream>>>((float4*)out, winner, ids, cells, count);
    main_k<<<4096, 256, 0, stream>>>(ids, cells, count, neighbors, xn4, xn1,
                                     w2aB8, w2bB, fwallB, out);
}

// Round 15
// 95.957 us; speedup vs baseline: 1.0951x; 1.0142x over previous
//
#include <hip/hip_runtime.h>

#define NPTS 65536
#define WW 1024
#define HWCELLS 65536
#define EPSF 1e-5f
#define QPTS 16

typedef __attribute__((ext_vector_type(8))) short short8;
typedef __attribute__((ext_vector_type(4))) float f32x4;

// tanh-form gelu via exp2+rcp: max |err| vs exact erf-gelu ~3e-4 (below bf16 rounding of g)
__device__ __forceinline__ float gelu_f(float x) {
    float x2 = x * x;
    float q  = fmaf(x2, -0.1029432f, -2.3022160f);   // -(2*0.7978845*[1, 0.044715])*log2(e)
    float e  = __builtin_amdgcn_exp2f(x * q);
    float r  = __builtin_amdgcn_rcpf(1.0f + e);
    return x * r;
}
__device__ __forceinline__ unsigned f2bf_rne(float x) {
    unsigned u = __float_as_uint(x);
    return (u + 0x7fffu + ((u >> 16) & 1u)) >> 16;
}
// HW packed f32x2 -> bf16x2 (RNE on gfx950)
__device__ __forceinline__ unsigned cvtpk(float lo, float hi) {
    unsigned r;
    asm("v_cvt_pk_bf16_f32 %0, %1, %2" : "=v"(r) : "v"(lo), "v"(hi));
    return r;
}

// blocks 0..255: repack pc + winner atomicMax;  block 256: weight folding + count=0;
// blocks 257..1280: out -1 prefill (independent work, rides the same dispatch)
__global__ void prepfold_k(const float* __restrict__ pc, const int* __restrict__ px,
                           const int* __restrict__ py,
                           float4* __restrict__ xn4, float* __restrict__ xn1,
                           int* __restrict__ winner, int* __restrict__ countp,
                           float4* __restrict__ out4,
                           const float* __restrict__ ng, const float* __restrict__ nbta,
                           const float* __restrict__ nm, const float* __restrict__ nv,
                           const float* __restrict__ w2a,
                           const float* __restrict__ g2a, const float* __restrict__ b2a,
                           const float* __restrict__ m2a, const float* __restrict__ v2a,
                           const float* __restrict__ g2b, const float* __restrict__ b2b,
                           const float* __restrict__ m2b, const float* __restrict__ v2b,
                           const float* __restrict__ w2b,
                           const float* __restrict__ c1w, const float* __restrict__ c1b,
                           const float* __restrict__ fw, const float* __restrict__ fbias,
                           unsigned short* __restrict__ w2aB8,
                           unsigned short* __restrict__ w2bB,
                           unsigned short* __restrict__ fwallB) {
    __shared__ float c1wS[640];
    __shared__ float c1adjS[128];
    const int t = threadIdx.x;

    if (blockIdx.x < 256) {
        int i = blockIdx.x * 256 + t;
        const float* p = &pc[(size_t)i * 5];
        xn4[i] = make_float4(p[0], p[1], p[2], p[3]);
        xn1[i] = p[4];
        int cell = py[i] * WW + px[i];
        atomicMax(&winner[cell], i);
        return;
    }
    if (blockIdx.x > 256) {
        // out prefill: 1024 blocks x 256 thr x 8 float4 = 2,097,152 float4
        int gid = (blockIdx.x - 257) * 256 + t;
        float4 mone = make_float4(-1.f, -1.f, -1.f, -1.f);
#pragma unroll
        for (int j = 0; j < 8; ++j) out4[gid + j * 262144] = mone;
        return;
    }

    // ---- fold block (all 256 threads participate in barriers; work on t<128) ----
    const int d = t;  // 0..127 used
    float s_n[5], t_n[5];
#pragma unroll
    for (int c = 0; c < 5; ++c) {
        s_n[c] = ng[c] * rsqrtf(nv[c] + EPSF);
        t_n[c] = nbta[c] - nm[c] * s_n[c];
    }
    for (int j = t; j < 640; j += 256) c1wS[j] = c1w[j];
    __syncthreads();
    if (t < 128) {
        float a = c1b[d];
#pragma unroll
        for (int c = 0; c < 5; ++c) a += c1wS[d * 5 + c] * t_n[c];
        c1adjS[d] = a;
    }
    __syncthreads();
    if (t >= 128) {
        if (t == 128) *countp = 0;   // zero the compaction counter each call
        return;
    }

    float s2b = g2b[d] * rsqrtf(v2b[d] + EPSF);
    float t2b = b2b[d] - m2b[d] * s2b;
    float acc = 0.f;
#pragma unroll
    for (int c = 0; c < 5; ++c) {
        float s2a = g2a[c] * rsqrtf(v2a[c] + EPSF);
        float t2a = b2a[c] - m2a[c] * s2a;
        float wv = w2a[d * 5 + c];
        w2aB8[d * 8 + c] = (unsigned short)f2bf_rne(s2b * wv * s2a * s_n[c]);
        acc += s2b * wv * t2a;
    }
    w2aB8[d * 8 + 5] = (unsigned short)f2bf_rne(acc + t2b);  // bias via dx[5]=1
    w2aB8[d * 8 + 6] = 0; w2aB8[d * 8 + 7] = 0;

#pragma unroll 8
    for (int i4 = 0; i4 < 32; ++i4) {
        float4 v = *(const float4*)&w2b[d * 128 + i4 * 4];
        unsigned short* dst = &w2bB[d * 128 + i4 * 4];
        dst[0] = (unsigned short)f2bf_rne(v.x);
        dst[1] = (unsigned short)f2bf_rne(v.y);
        dst[2] = (unsigned short)f2bf_rne(v.z);
        dst[3] = (unsigned short)f2bf_rne(v.w);
    }

    float f1[5] = {0.f, 0.f, 0.f, 0.f, 0.f};
    float fbv = fbias[d];
#pragma unroll 8
    for (int d4 = 0; d4 < 32; ++d4) {
        float4 fv = *(const float4*)&fw[d * 256 + d4 * 4];
        float4 fn = *(const float4*)&fw[d * 256 + 128 + d4 * 4];
        unsigned short* dst = &fwallB[d * 160 + d4 * 4];
        dst[0] = (unsigned short)f2bf_rne(fn.x);
        dst[1] = (unsigned short)f2bf_rne(fn.y);
        dst[2] = (unsigned short)f2bf_rne(fn.z);
        dst[3] = (unsigned short)f2bf_rne(fn.w);
        int dd = d4 * 4;
        fbv += fv.x * c1adjS[dd] + fv.y * c1adjS[dd+1] + fv.z * c1adjS[dd+2] + fv.w * c1adjS[dd+3];
#pragma unroll
        for (int c = 0; c < 5; ++c)
            f1[c] += fv.x * c1wS[dd*5 + c] + fv.y * c1wS[(dd+1)*5 + c]
                   + fv.z * c1wS[(dd+2)*5 + c] + fv.w * c1wS[(dd+3)*5 + c];
    }
#pragma unroll
    for (int c = 0; c < 5; ++c)
        fwallB[d * 160 + 128 + c] = (unsigned short)f2bf_rne(f1[c] * s_n[c]);
    fwallB[d * 160 + 133] = (unsigned short)f2bf_rne(fbv);
    for (int j = 134; j < 160; ++j) fwallB[d * 160 + j] = 0;
}

// 256 blocks: count own group's winners, atomicAdd for a group base slot,
// fill ids/cells (cell-ascending WITHIN group) — tiny critical-path kernel
__global__ void cntfill_k(const int* __restrict__ winner,
                          int* __restrict__ ids, int* __restrict__ cells,
                          int* __restrict__ countp) {
    __shared__ int wcnt[4];
    __shared__ int gbase;
    int lane = threadIdx.x & 63, wv = threadIdx.x >> 6;
    int cell = blockIdx.x * 256 + threadIdx.x;
    int win = winner[cell];
    bool occ = win >= 0;
    unsigned long long m = __ballot(occ);
    if (lane == 0) wcnt[wv] = __popcll(m);
    __syncthreads();
    if (threadIdx.x == 0) {
        int c = wcnt[0] + wcnt[1] + wcnt[2] + wcnt[3];
        gbase = atomicAdd(countp, c);
    }
    __syncthreads();
    int woff = gbase;
    for (int i = 0; i < wv; ++i) woff += wcnt[i];
    if (occ) {
        int lrank = __popcll(m & ((1ull << lane) - 1));
        ids[woff + lrank] = win;
        cells[woff + lrank] = cell;
    }
}

// fused MFMA main: 16 pts/block, 256 thr (4 waves); no global traffic in k-loop
// (byte-identical to the round-8 proven body)
__launch_bounds__(256, 6)
__global__ void main_k(const int* __restrict__ ids, const int* __restrict__ cells,
                       const int* __restrict__ countp,
                       const int* __restrict__ nbrs,
                       const float4* __restrict__ xn4, const float* __restrict__ xn1,
                       const unsigned short* __restrict__ w2aB8,
                       const unsigned short* __restrict__ w2bB,
                       const unsigned short* __restrict__ fwallB,
                       float* __restrict__ outp) {
    const int cnt = *countp;
    const int n0 = blockIdx.x * QPTS;
    if (n0 >= cnt) return;

    __shared__ char           lds[8192];          // G dbuf (2x4096); M (5120) overlays
    __shared__ unsigned short dxS[15 * 16 * 8];   // bf16 [kk][pt][8]: dx0..4,1.0,0,0
    __shared__ int   idS[QPTS];
    __shared__ int   nbS[QPTS * 16];
    __shared__ float xnS[QPTS][5];
    __shared__ int   cellS[QPTS];

    const int t = threadIdx.x;
    const int w = t >> 6;
    const int l = t & 63;
    const int l15 = l & 15;
    const int lg  = l >> 4;

    if (t < QPTS) {
        int slot = n0 + t;
        slot = slot < cnt ? slot : cnt - 1;
        idS[t] = ids[slot];
        cellS[t] = cells[slot];
    }
    __syncthreads();

    nbS[t] = nbrs[idS[t >> 4] * 16 + (t & 15)];
    if (t < QPTS) {
        int id = idS[t];
        float4 a = xn4[id];
        xnS[t][0] = a.x; xnS[t][1] = a.y; xnS[t][2] = a.z; xnS[t][3] = a.w;
        xnS[t][4] = xn1[id];
    }

    // A1: folded W2A'|bias rows (only lg==0 lanes carry k=0..7; rest zero)
    short8 a1[2] = { {0,0,0,0,0,0,0,0}, {0,0,0,0,0,0,0,0} };
    if (lg == 0) {
        a1[0] = *(const short8*)(w2aB8 + (w * 32 + l15) * 8);
        a1[1] = *(const short8*)(w2aB8 + (w * 32 + 16 + l15) * 8);
    }
    // A2: w2b rows [w*32, w*32+32), K=128
    short8 a2[2][4];
#pragma unroll
    for (int rt = 0; rt < 2; ++rt)
#pragma unroll
        for (int ks = 0; ks < 4; ++ks)
            a2[rt][ks] = *(const short8*)(w2bB + (w * 32 + rt * 16 + l15) * 128 + ks * 32 + lg * 8);

    __syncthreads();  // nbS + xnS ready

    // build dx tile: one gather per (pt,kk)
    if (t < 240) {
        int pt = t & 15, kk = t >> 4;
        int nb = nbS[pt * 16 + kk + 1];
        float4 a = xn4[nb];
        float  e = xn1[nb];
        float d0 = a.x - xnS[pt][0];
        float d1 = a.y - xnS[pt][1];
        float d2 = a.z - xnS[pt][2];
        float d3 = a.w - xnS[pt][3];
        float d4 = e   - xnS[pt][4];
        uint4 v;
        v.x = cvtpk(d0, d1);
        v.y = cvtpk(d2, d3);
        v.z = cvtpk(d4, 1.0f);
        v.w = 0u;
        *(uint4*)&dxS[(kk * 16 + pt) * 8] = v;
    }
    __syncthreads();  // dxS ready

    const f32x4 zero4 = {0.f, 0.f, 0.f, 0.f};
    f32x4 mmax[2];
#pragma unroll
    for (int rt = 0; rt < 2; ++rt)
#pragma unroll
        for (int j = 0; j < 4; ++j) mmax[rt][j] = -1e30f;

    for (int kk = 0; kk < 15; ++kk) {
        // MFMA1: s[din][pt] = W2A'|b2 @ [dx;1]  (broadcast LDS read; lg!=0 rows of A are 0)
        short8 dxf = *(const short8*)&dxS[(kk * 16 + l15) * 8];
        char* Gb = lds + (kk & 1) * 4096;
#pragma unroll
        for (int rt = 0; rt < 2; ++rt) {
            f32x4 s = __builtin_amdgcn_mfma_f32_16x16x32_bf16(a1[rt], dxf, zero4, 0, 0, 0);
            uint2 pr;
            pr.x = cvtpk(gelu_f(s[0]), gelu_f(s[1]));
            pr.y = cvtpk(gelu_f(s[2]), gelu_f(s[3]));
            int din0 = w * 32 + rt * 16 + lg * 4;
            *(uint2*)(Gb + l15 * 256 + ((din0 * 2) ^ (l15 << 4))) = pr;
        }
        __syncthreads();
        // MFMA2: u = w2b @ G; running max
        f32x4 acc[2];
        __builtin_amdgcn_s_setprio(1);
#pragma unroll
        for (int ks = 0; ks < 4; ++ks) {
            int kb = (ks * 32 + lg * 8) * 2;
            short8 bfrag = *(const short8*)(Gb + l15 * 256 + (kb ^ (l15 << 4)));
#pragma unroll
            for (int rt = 0; rt < 2; ++rt)
                acc[rt] = __builtin_amdgcn_mfma_f32_16x16x32_bf16(
                    a2[rt][ks], bfrag, ks == 0 ? zero4 : acc[rt], 0, 0, 0);
        }
        __builtin_amdgcn_s_setprio(0);
#pragma unroll
        for (int rt = 0; rt < 2; ++rt)
#pragma unroll
            for (int j = 0; j < 4; ++j)
                mmax[rt][j] = fmaxf(mmax[rt][j], acc[rt][j]);
    }

    __syncthreads();  // all MFMA2 reads done before M overlay

    // running max -> M [pt][k] bf16 (k<128 swizzled) + xn|1 tail (k=128..)
    {
        char* Mb = lds;
        int sw = l15 << 4;
#pragma unroll
        for (int rt = 0; rt < 2; ++rt) {
            int dout = w * 32 + rt * 16 + lg * 4;
            unsigned lo = cvtpk(mmax[rt][0], mmax[rt][1]);
            unsigned hi = cvtpk(mmax[rt][2], mmax[rt][3]);
            *(unsigned*)(Mb + l15 * 320 + ((dout * 2) ^ sw)) = lo;
            *(unsigned*)(Mb + l15 * 320 + (((dout + 2) * 2) ^ sw)) = hi;
        }
        if (t < QPTS) {
            uint4 a;
            a.x = cvtpk(xnS[t][0], xnS[t][1]);
            a.y = cvtpk(xnS[t][2], xnS[t][3]);
            a.z = cvtpk(xnS[t][4], 1.0f);
            a.w = 0u;
            uint4 z; z.x = 0u; z.y = 0u; z.z = 0u; z.w = 0u;
            *(uint4*)(Mb + t * 320 + 256) = a;
            *(uint4*)(Mb + t * 320 + 272) = z;
            *(uint4*)(Mb + t * 320 + 288) = z;
            *(uint4*)(Mb + t * 320 + 304) = z;
        }
    }
    __syncthreads();

    // final GEMM: feats[e][pt] = fwallB(128x160) @ M(160xQPTS)
    f32x4 facc[2];
    const char* Mr = lds;
#pragma unroll
    for (int ks = 0; ks < 5; ++ks) {
        short8 af[2];
#pragma unroll
        for (int rt = 0; rt < 2; ++rt)
            af[rt] = *(const short8*)(fwallB + (w * 32 + rt * 16 + l15) * 160 + ks * 32 + lg * 8);
        int kb = (ks * 32 + lg * 8) * 2;
        int kbs = (kb < 256) ? (kb ^ (l15 << 4)) : kb;
        short8 bfr = *(const short8*)(Mr + l15 * 320 + kbs);
#pragma unroll
        for (int rt = 0; rt < 2; ++rt)
            facc[rt] = __builtin_amdgcn_mfma_f32_16x16x32_bf16(
                af[rt], bfr, ks == 0 ? zero4 : facc[rt], 0, 0, 0);
    }

    // direct scatter: cells ascending within group -> near-coalesced lines
    const int cell = cellS[l15];
#pragma unroll
    for (int rt = 0; rt < 2; ++rt) {
        int e0 = w * 32 + rt * 16 + lg * 4;
#pragma unroll
        for (int j = 0; j < 4; ++j)
            outp[(size_t)(e0 + j) * HWCELLS + cell] = facc[rt][j];
    }
}

extern "C" void kernel_launch(void* const* d_in, const int* in_sizes, int n_in,
                              void* d_out, int out_size, void* d_ws, size_t ws_size,
                              hipStream_t stream) {
    const float* pc        = (const float*)d_in[0];
    const int*   neighbors = (const int*)d_in[1];
    const int*   px        = (const int*)d_in[2];
    const int*   py        = (const int*)d_in[3];
    const float* norm_g    = (const float*)d_in[4];
    const float* norm_b    = (const float*)d_in[5];
    const float* norm_m    = (const float*)d_in[6];
    const float* norm_v    = (const float*)d_in[7];
    const float* conv1_w   = (const float*)d_in[8];
    const float* conv1_b   = (const float*)d_in[9];
    const float* bn2a_g    = (const float*)d_in[10];
    const float* bn2a_b    = (const float*)d_in[11];
    const float* bn2a_m    = (const float*)d_in[12];
    const float* bn2a_v    = (const float*)d_in[13];
    const float* w2a       = (const float*)d_in[14];
    const float* bn2b_g    = (const float*)d_in[15];
    const float* bn2b_b    = (const float*)d_in[16];
    const float* bn2b_m    = (const float*)d_in[17];
    const float* bn2b_v    = (const float*)d_in[18];
    const float* w2b       = (const float*)d_in[19];
    const float* final_w   = (const float*)d_in[20];
    const float* final_b   = (const float*)d_in[21];
    float* out = (float*)d_out;

    char* ws = (char*)d_ws;
    float4*         xn4      = (float4*)(ws);                     // 1,048,576 B
    float*          xn1      = (float*)(ws + 1048576);            //   262,144 B
    int*            winner   = (int*)(ws + 1310720);              //   262,144 B
    int*            ids      = (int*)(ws + 1572864);              //   262,144 B
    int*            cells    = (int*)(ws + 1835008);              //   262,144 B
    int*            count    = (int*)(ws + 2097152);              //       256 B
    unsigned short* w2aB8    = (unsigned short*)(ws + 2097408);   //     2,048 B
    unsigned short* w2bB     = (unsigned short*)(ws + 2099456);   //    32,768 B
    unsigned short* fwallB   = (unsigned short*)(ws + 2132224);   //    40,960 B

    // winner = -1 via byte-fill (graph-capture-safe async memset)
    hipMemsetAsync(winner, 0xFF, 262144, stream);
    prepfold_k<<<1281, 256, 0, stream>>>(pc, px, py, xn4, xn1, winner, count,
                                         (float4*)out,
                                         norm_g, norm_b, norm_m, norm_v,
                                         w2a, bn2a_g, bn2a_b, bn2a_m, bn2a_v,
                                         bn2b_g, bn2b_b, bn2b_m, bn2b_v, w2b,
                                         conv1_w, conv1_b, final_w, final_b,
                                         w2aB8, w2bB, fwallB);
    cntfill_k<<<256, 256, 0, stream>>>(winner, ids, cells, count);
    main_k<<<4096, 256, 0, stream>>>(ids, cells, count, neighbors, xn4, xn1,
                                     w2aB8, w2bB, fwallB, out);
}